// Round 3
// baseline (715.541 us; speedup 1.0000x reference)
//
#include <hip/hip_runtime.h>
#include <hip/hip_bf16.h>
#include <math.h>

#define T_LEN 512
#define B_SZ  256
#define I_SZ  300
#define H_SZ  64
#define G3    192   // 3H

typedef float    f4v __attribute__((ext_vector_type(4)));
typedef short    s8v __attribute__((ext_vector_type(8)));
typedef _Float16 h2v __attribute__((ext_vector_type(2)));

#if __has_builtin(__builtin_amdgcn_fdot2)
#define FDOT2(a, b, c) __builtin_amdgcn_fdot2((a), (b), (c), false)
#else
#define FDOT2(a, b, c) ((c) + (float)(a).x * (float)(b).x + (float)(a).y * (float)(b).y)
#endif

// split fp32 -> hi bf16 + lo bf16 (residual), round-to-nearest-even
__device__ __forceinline__ void split_bf16(float x, unsigned short& hi, unsigned short& lo) {
    unsigned u = __builtin_bit_cast(unsigned, x);
    unsigned h = (u + 0x7FFFu + ((u >> 16) & 1u)) >> 16;
    hi = (unsigned short)h;
    float hf = __builtin_bit_cast(float, h << 16);
    float l = x - hf;
    unsigned ul = __builtin_bit_cast(unsigned, l);
    lo = (unsigned short)((ul + 0x7FFFu + ((ul >> 16) & 1u)) >> 16);
}

// ---------------------------------------------------------------------------
// Kernel 1: input projection via split-bf16 MFMA, f16 output, pipelined loads.
//   C[m=(t,b)][n=(d,g)] = X[m][k] . W[n][k] + bias[n]
// ---------------------------------------------------------------------------
#define NKC 10

__global__ __launch_bounds__(256) void proj_gemm(
    const float* __restrict__ x,
    const float* __restrict__ Wf, const float* __restrict__ bf,
    const float* __restrict__ Wb, const float* __restrict__ bb,
    _Float16* __restrict__ xp)
{
    __shared__ unsigned short Ahi[128 * 32];
    __shared__ unsigned short Alo[128 * 32];
    __shared__ unsigned short Bhi[192 * 32];
    __shared__ unsigned short Blo[192 * 32];

    const int tid = threadIdx.x;
    const int d   = blockIdx.x;            // direction (N-block)
    const int m0  = blockIdx.y * 128;
    const int t_blk = m0 >> 8;
    const int b0    = m0 & 255;

    const float* W    = d ? Wb : Wf;
    const float* bias = d ? bb : bf;

    const int srow = tid >> 3;             // 0..31
    const int sq   = tid & 7;              // float4 index (k = sq*4)

    const int lane = tid & 63;
    const int w    = tid >> 6;
    const int wm   = (w & 1) * 64;
    const int wn   = (w >> 1) * 96;
    const int frow = lane & 15;
    const int kq   = lane >> 4;

    const float* aptr[4];
    #pragma unroll
    for (int p = 0; p < 4; ++p)
        aptr[p] = x + (size_t)((b0 + p * 32 + srow) * T_LEN + t_blk) * I_SZ + sq * 4;
    const float* bptr[6];
    #pragma unroll
    for (int p = 0; p < 6; ++p)
        bptr[p] = W + (size_t)(p * 32 + srow) * I_SZ + sq * 4;

    f4v acc[4][6];
    #pragma unroll
    for (int mt = 0; mt < 4; ++mt)
        #pragma unroll
        for (int nt = 0; nt < 6; ++nt) acc[mt][nt] = (f4v)0.f;

    // prefetch chunk 0
    float4 av[4], bv[6];
    {
        const bool valid = (sq * 4) < 297;
        #pragma unroll
        for (int p = 0; p < 4; ++p)
            av[p] = valid ? *(const float4*)aptr[p] : float4{0.f, 0.f, 0.f, 0.f};
        #pragma unroll
        for (int p = 0; p < 6; ++p)
            bv[p] = valid ? *(const float4*)bptr[p] : float4{0.f, 0.f, 0.f, 0.f};
    }

    for (int kc = 0; kc < NKC; ++kc) {
        __syncthreads();   // previous chunk's fragment reads done

        // ---- convert + LDS write (consumes av/bv) ----
        #pragma unroll
        for (int p = 0; p < 4; ++p) {
            int row = p * 32 + srow;
            ushort4 h4, l4;
            split_bf16(av[p].x, h4.x, l4.x); split_bf16(av[p].y, h4.y, l4.y);
            split_bf16(av[p].z, h4.z, l4.z); split_bf16(av[p].w, h4.w, l4.w);
            *(ushort4*)&Ahi[row * 32 + sq * 4] = h4;
            *(ushort4*)&Alo[row * 32 + sq * 4] = l4;
        }
        #pragma unroll
        for (int p = 0; p < 6; ++p) {
            int row = p * 32 + srow;
            ushort4 h4, l4;
            split_bf16(bv[p].x, h4.x, l4.x); split_bf16(bv[p].y, h4.y, l4.y);
            split_bf16(bv[p].z, h4.z, l4.z); split_bf16(bv[p].w, h4.w, l4.w);
            *(ushort4*)&Bhi[row * 32 + sq * 4] = h4;
            *(ushort4*)&Blo[row * 32 + sq * 4] = l4;
        }
        __syncthreads();

        // ---- issue next chunk's loads (in flight during MFMAs) ----
        if (kc + 1 < NKC) {
            const int k0 = (kc + 1) * 32;
            const bool valid = (k0 + sq * 4) < 297;
            #pragma unroll
            for (int p = 0; p < 4; ++p)
                av[p] = valid ? *(const float4*)(aptr[p] + k0) : float4{0.f, 0.f, 0.f, 0.f};
            #pragma unroll
            for (int p = 0; p < 6; ++p)
                bv[p] = valid ? *(const float4*)(bptr[p] + k0) : float4{0.f, 0.f, 0.f, 0.f};
        }

        // ---- fragment loads + MFMA ----
        s8v bh_[6], bl_[6];
        #pragma unroll
        for (int nt = 0; nt < 6; ++nt) {
            int off = (wn + nt * 16 + frow) * 32 + kq * 8;
            bh_[nt] = *(const s8v*)&Bhi[off];
            bl_[nt] = *(const s8v*)&Blo[off];
        }
        #pragma unroll
        for (int mt = 0; mt < 4; ++mt) {
            int off = (wm + mt * 16 + frow) * 32 + kq * 8;
            s8v ah = *(const s8v*)&Ahi[off];
            s8v al = *(const s8v*)&Alo[off];
            #pragma unroll
            for (int nt = 0; nt < 6; ++nt) {
                acc[mt][nt] = __builtin_amdgcn_mfma_f32_16x16x32_bf16(al, bh_[nt], acc[mt][nt], 0, 0, 0);
                acc[mt][nt] = __builtin_amdgcn_mfma_f32_16x16x32_bf16(ah, bl_[nt], acc[mt][nt], 0, 0, 0);
                acc[mt][nt] = __builtin_amdgcn_mfma_f32_16x16x32_bf16(ah, bh_[nt], acc[mt][nt], 0, 0, 0);
            }
        }
    }

    // ---- epilogue: bias + f16 store ----
    const int col  = lane & 15;
    const int rowq = lane >> 4;
    float bias_v[6];
    #pragma unroll
    for (int nt = 0; nt < 6; ++nt) bias_v[nt] = bias[wn + nt * 16 + col];

    #pragma unroll
    for (int mt = 0; mt < 4; ++mt) {
        #pragma unroll
        for (int reg = 0; reg < 4; ++reg) {
            int b = b0 + wm + mt * 16 + rowq * 4 + reg;
            _Float16* o = xp + ((size_t)(d * T_LEN + t_blk) * B_SZ + b) * G3;
            #pragma unroll
            for (int nt = 0; nt < 6; ++nt) {
                int g = wn + nt * 16 + col;
                o[g] = (_Float16)(acc[mt][nt][reg] + bias_v[nt]);
            }
        }
    }
}

// ---------------------------------------------------------------------------
// Kernel 2: GRU scan — one wave per (dir,batch), barrier-free step loop.
// Lane i owns gates {i, 64+i, 128+i}; W_hh rows in packed-f16 VGPRs.
// h round-trips through 128 B of LDS: 1 ds_write_b16 + 32 uniform ds_read_b32.
// ---------------------------------------------------------------------------
#define PF 4

__device__ __forceinline__ float sigm_f(float x) {
    return __builtin_amdgcn_rcpf(1.f + __expf(-x));
}
__device__ __forceinline__ float tanh_f(float x) {
    float a = fabsf(x);
    float e = __expf(2.f * a);
    float t = 1.f - 2.f * __builtin_amdgcn_rcpf(1.f + e);
    return copysignf(t, x);
}

__global__ __launch_bounds__(64) void gru_scan(
    const _Float16* __restrict__ xp,
    const float* __restrict__ Whf, const float* __restrict__ bhf,
    const float* __restrict__ Whb, const float* __restrict__ bhb,
    float* __restrict__ feat)
{
    const int lane = threadIdx.x;
    const int bid  = blockIdx.x;       // 0..511
    const int d    = bid >> 8;
    const int b    = bid & 255;

    const float* Whh = d ? Whb : Whf;
    const float* bhh = d ? bhb : bhf;

    // W_hh rows for this lane's 3 gates, packed f16 pairs (96 VGPRs)
    h2v wr[32], wz[32], wn[32];
    {
        const float2* r0 = (const float2*)(Whh + (size_t)lane * 64);
        const float2* r1 = (const float2*)(Whh + (size_t)(64 + lane) * 64);
        const float2* r2 = (const float2*)(Whh + (size_t)(128 + lane) * 64);
        #pragma unroll
        for (int k = 0; k < 32; ++k) {
            float2 a = r0[k], c = r1[k], e = r2[k];
            wr[k] = h2v{(_Float16)a.x, (_Float16)a.y};
            wz[k] = h2v{(_Float16)c.x, (_Float16)c.y};
            wn[k] = h2v{(_Float16)e.x, (_Float16)e.y};
        }
    }
    const float bhr = bhh[lane], bhz = bhh[64 + lane], bhn = bhh[128 + lane];

    __shared__ _Float16 h16s[64];
    h16s[lane] = (_Float16)0.f;
    float hreg = 0.f;
    __syncthreads();

    const long sstep = d ? -(long)(B_SZ * G3) : (long)(B_SZ * G3);
    const _Float16* xb0 = xp + ((size_t)(d ? (2 * T_LEN - 1) : 0) * B_SZ + b) * G3;

    // register prefetch ring, PF steps deep
    _Float16 pr[PF], pz[PF], pn[PF];
    #pragma unroll
    for (int j = 0; j < PF; ++j) {
        const _Float16* p = xb0 + j * sstep;
        pr[j] = p[lane]; pz[j] = p[64 + lane]; pn[j] = p[128 + lane];
    }
    const _Float16* pf = xb0 + PF * sstep;

    const h2v* hp = (const h2v*)h16s;

    for (int sb = 0; sb < T_LEN; sb += PF) {
        #pragma unroll
        for (int j = 0; j < PF; ++j) {
            const int s = sb + j;
            float xr = (float)pr[j], xz = (float)pz[j], xn = (float)pn[j];
            if (s + PF < T_LEN) {            // uniform branch; refill slot j
                pr[j] = pf[lane]; pz[j] = pf[64 + lane]; pn[j] = pf[128 + lane];
            }
            pf += sstep;

            float ar0 = 0.f, ar1 = 0.f, az0 = 0.f, az1 = 0.f, an0 = 0.f, an1 = 0.f;
            #pragma unroll
            for (int k = 0; k < 32; k += 2) {
                h2v h0 = hp[k], h1 = hp[k + 1];   // uniform ds_read_b32 (broadcast)
                ar0 = FDOT2(wr[k],     h0, ar0);
                az0 = FDOT2(wz[k],     h0, az0);
                an0 = FDOT2(wn[k],     h0, an0);
                ar1 = FDOT2(wr[k + 1], h1, ar1);
                az1 = FDOT2(wz[k + 1], h1, az1);
                an1 = FDOT2(wn[k + 1], h1, an1);
            }
            float r  = sigm_f(xr + bhr + ar0 + ar1);
            float z  = sigm_f(xz + bhz + az0 + az1);
            float hn = bhn + an0 + an1;
            float n  = tanh_f(xn + r * hn);
            hreg = (1.f - z) * n + z * hreg;
            h16s[lane] = (_Float16)hreg;       // ds_write_b16; in-order LDS pipe,
                                               // single wave -> no barrier needed
            if (s == 0)         feat[b * 256 + (d ? 192 : 0) + lane] = hreg;
            if (s == T_LEN - 1) feat[b * 256 + (d ? 64 : 128) + lane] = hreg;
        }
    }
}

// ---------------------------------------------------------------------------
// Kernel 3: MLP head. feat[b][256] -> 32 (LeakyReLU) -> 1
// ---------------------------------------------------------------------------
__global__ __launch_bounds__(64) void head_k(
    const float* __restrict__ feat,
    const float* __restrict__ W1, const float* __restrict__ b1,
    const float* __restrict__ W2, const float* __restrict__ b2,
    float* __restrict__ out)
{
    __shared__ float fs[256];
    const int b = blockIdx.x;
    const int tid = threadIdx.x;
    *(float4*)&fs[tid * 4] = *(const float4*)&feat[b * 256 + tid * 4];
    __syncthreads();
    float v = 0.f;
    if (tid < 32) {
        float a = b1[tid];
        const float4* Wv = (const float4*)(W1 + tid * 256);
        const float4* fv = (const float4*)fs;
        #pragma unroll 8
        for (int k = 0; k < 64; ++k) {
            float4 wv = Wv[k], f = fv[k];
            a += wv.x * f.x + wv.y * f.y + wv.z * f.z + wv.w * f.w;
        }
        a = a >= 0.f ? a : 0.01f * a;
        v = a * W2[tid];
    }
    #pragma unroll
    for (int off = 16; off > 0; off >>= 1) v += __shfl_down(v, off);
    if (tid == 0) out[b] = v + b2[0];
}

// ---------------------------------------------------------------------------
extern "C" void kernel_launch(void* const* d_in, const int* in_sizes, int n_in,
                              void* d_out, int out_size, void* d_ws, size_t ws_size,
                              hipStream_t stream)
{
    const float* x    = (const float*)d_in[0];
    const float* Wihf = (const float*)d_in[1];
    const float* Whhf = (const float*)d_in[2];
    const float* bihf = (const float*)d_in[3];
    const float* bhhf = (const float*)d_in[4];
    const float* Wihb = (const float*)d_in[5];
    const float* Whhb = (const float*)d_in[6];
    const float* bihb = (const float*)d_in[7];
    const float* bhhb = (const float*)d_in[8];
    const float* W1   = (const float*)d_in[9];
    const float* b1   = (const float*)d_in[10];
    const float* W2   = (const float*)d_in[11];
    const float* b2   = (const float*)d_in[12];
    float* out = (float*)d_out;

    _Float16* xp16 = (_Float16*)d_ws;                        // 2*512*256*192 f16 = 100.7 MB
    float*    feat = (float*)((char*)d_ws + (size_t)2 * T_LEN * B_SZ * G3 * 2);

    dim3 gg(2, 1024);
    proj_gemm<<<gg, 256, 0, stream>>>(x, Wihf, bihf, Wihb, bihb, xp16);
    gru_scan<<<512, 64, 0, stream>>>(xp16, Whhf, bhhf, Whhb, bhhb, feat);
    head_k<<<256, 64, 0, stream>>>(feat, W1, b1, W2, b2, out);
}

// Round 4
// 696.849 us; speedup vs baseline: 1.0268x; 1.0268x over previous
//
#include <hip/hip_runtime.h>
#include <hip/hip_bf16.h>
#include <math.h>

#define T_LEN 512
#define B_SZ  256
#define I_SZ  300
#define H_SZ  64
#define G3    192   // 3H

typedef float    f4v __attribute__((ext_vector_type(4)));
typedef _Float16 h4v __attribute__((ext_vector_type(4)));
typedef _Float16 h8v __attribute__((ext_vector_type(8)));

// ---------------------------------------------------------------------------
// Kernel 1: input projection, single-MFMA f16 path.
//   C[m=(t,b)][n=(d,g)] = X[m][k] . W[n][k] + bias[n]
//   f16 rounding error ~|x| 2^-11 per factor -> xp err ~5e-4 (fits threshold).
// ---------------------------------------------------------------------------
#define NKC 10

__global__ __launch_bounds__(256) void proj_gemm(
    const float* __restrict__ x,
    const float* __restrict__ Wf, const float* __restrict__ bf,
    const float* __restrict__ Wb, const float* __restrict__ bb,
    _Float16* __restrict__ xp)
{
    __shared__ _Float16 Ah[128 * 32];   // 8 KB
    __shared__ _Float16 Bh[192 * 32];   // 12 KB

    const int tid = threadIdx.x;
    const int d   = blockIdx.x;            // direction (N-block)
    const int m0  = blockIdx.y * 128;
    const int t_blk = m0 >> 8;
    const int b0    = m0 & 255;

    const float* W    = d ? Wb : Wf;
    const float* bias = d ? bb : bf;

    const int srow = tid >> 3;             // 0..31
    const int sq   = tid & 7;              // float4 index (k = sq*4)

    const int lane = tid & 63;
    const int w    = tid >> 6;
    const int wm   = (w & 1) * 64;
    const int wn   = (w >> 1) * 96;
    const int frow = lane & 15;
    const int kq   = lane >> 4;

    const float* aptr[4];
    #pragma unroll
    for (int p = 0; p < 4; ++p)
        aptr[p] = x + (size_t)((b0 + p * 32 + srow) * T_LEN + t_blk) * I_SZ + sq * 4;
    const float* bptr[6];
    #pragma unroll
    for (int p = 0; p < 6; ++p)
        bptr[p] = W + (size_t)(p * 32 + srow) * I_SZ + sq * 4;

    f4v acc[4][6];
    #pragma unroll
    for (int mt = 0; mt < 4; ++mt)
        #pragma unroll
        for (int nt = 0; nt < 6; ++nt) acc[mt][nt] = (f4v)0.f;

    // prefetch chunk 0
    float4 av[4], bv[6];
    {
        const bool valid = (sq * 4) < 297;
        #pragma unroll
        for (int p = 0; p < 4; ++p)
            av[p] = valid ? *(const float4*)aptr[p] : float4{0.f, 0.f, 0.f, 0.f};
        #pragma unroll
        for (int p = 0; p < 6; ++p)
            bv[p] = valid ? *(const float4*)bptr[p] : float4{0.f, 0.f, 0.f, 0.f};
    }

    for (int kc = 0; kc < NKC; ++kc) {
        __syncthreads();   // previous chunk's fragment reads done

        // ---- convert to f16 + LDS write ----
        #pragma unroll
        for (int p = 0; p < 4; ++p) {
            int row = p * 32 + srow;
            h4v c = { (_Float16)av[p].x, (_Float16)av[p].y,
                      (_Float16)av[p].z, (_Float16)av[p].w };
            *(h4v*)&Ah[row * 32 + sq * 4] = c;
        }
        #pragma unroll
        for (int p = 0; p < 6; ++p) {
            int row = p * 32 + srow;
            h4v c = { (_Float16)bv[p].x, (_Float16)bv[p].y,
                      (_Float16)bv[p].z, (_Float16)bv[p].w };
            *(h4v*)&Bh[row * 32 + sq * 4] = c;
        }
        __syncthreads();

        // ---- issue next chunk's loads (fly during MFMAs) ----
        if (kc + 1 < NKC) {
            const int k0 = (kc + 1) * 32;
            const bool valid = (k0 + sq * 4) < 297;
            #pragma unroll
            for (int p = 0; p < 4; ++p)
                av[p] = valid ? *(const float4*)(aptr[p] + k0) : float4{0.f, 0.f, 0.f, 0.f};
            #pragma unroll
            for (int p = 0; p < 6; ++p)
                bv[p] = valid ? *(const float4*)(bptr[p] + k0) : float4{0.f, 0.f, 0.f, 0.f};
        }

        // ---- fragment loads + MFMA ----
        h8v bh_[6];
        #pragma unroll
        for (int nt = 0; nt < 6; ++nt)
            bh_[nt] = *(const h8v*)&Bh[(wn + nt * 16 + frow) * 32 + kq * 8];
        #pragma unroll
        for (int mt = 0; mt < 4; ++mt) {
            h8v ah = *(const h8v*)&Ah[(wm + mt * 16 + frow) * 32 + kq * 8];
            #pragma unroll
            for (int nt = 0; nt < 6; ++nt)
                acc[mt][nt] = __builtin_amdgcn_mfma_f32_16x16x32_f16(ah, bh_[nt], acc[mt][nt], 0, 0, 0);
        }
    }

    // ---- epilogue: bias + f16 store ----
    const int col  = lane & 15;
    const int rowq = lane >> 4;
    float bias_v[6];
    #pragma unroll
    for (int nt = 0; nt < 6; ++nt) bias_v[nt] = bias[wn + nt * 16 + col];

    #pragma unroll
    for (int mt = 0; mt < 4; ++mt) {
        #pragma unroll
        for (int reg = 0; reg < 4; ++reg) {
            int b = b0 + wm + mt * 16 + rowq * 4 + reg;
            _Float16* o = xp + ((size_t)(d * T_LEN + t_blk) * B_SZ + b) * G3;
            #pragma unroll
            for (int nt = 0; nt < 6; ++nt) {
                int g = wn + nt * 16 + col;
                o[g] = (_Float16)(acc[mt][nt][reg] + bias_v[nt]);
            }
        }
    }
}

// ---------------------------------------------------------------------------
// Kernel 2: GRU scan — 3 waves per sequence, one wave per gate type (r/z/n).
// Each wave holds 64 f32 W-rows (64 VGPRs), leaving ~150 free regs so the
// compiler can hoist the 16 uniform ds_read_b128 h-loads (R3's serialization
// was register-pressure-induced: 96 W-regs left no room to hoist).
// ---------------------------------------------------------------------------
#define PF 4

__device__ __forceinline__ float sigm_f(float x) {
    return __builtin_amdgcn_rcpf(1.f + __expf(-x));
}
__device__ __forceinline__ float tanh_f(float x) {
    float a = fabsf(x);
    float e = __expf(2.f * a);
    float t = 1.f - 2.f * __builtin_amdgcn_rcpf(1.f + e);
    return copysignf(t, x);
}

__global__ __launch_bounds__(192) void gru_scan(
    const _Float16* __restrict__ xp,
    const float* __restrict__ Whf, const float* __restrict__ bhf,
    const float* __restrict__ Whb, const float* __restrict__ bhb,
    float* __restrict__ feat)
{
    const int tid  = threadIdx.x;
    const int lane = tid & 63;
    const int wg   = tid >> 6;         // 0=r, 1=z, 2=n
    const int bid  = blockIdx.x;       // 0..511
    const int d    = bid >> 8;
    const int b    = bid & 255;

    const float* Whh = d ? Whb : Whf;
    const float* bhh = d ? bhb : bhf;
    const int row = wg * 64 + lane;

    float4 w4[16];
    #pragma unroll
    for (int k = 0; k < 16; ++k)
        w4[k] = *(const float4*)(Whh + (size_t)row * 64 + k * 4);
    const float bh = bhh[row];

    __shared__ __align__(16) float h_s[64];
    __shared__ float r_s[64];
    __shared__ float z_s[64];
    if (tid < 64) h_s[tid] = 0.f;
    float hreg = 0.f;
    __syncthreads();

    const long sstep = d ? -(long)(B_SZ * G3) : (long)(B_SZ * G3);
    const _Float16* xb = xp + ((size_t)(d ? (2 * T_LEN - 1) : 0) * B_SZ + b) * G3 + row;

    float pr[PF];
    #pragma unroll
    for (int j = 0; j < PF; ++j) pr[j] = (float)xb[j * sstep];
    const _Float16* pf = xb + PF * sstep;

    const float4* h4 = (const float4*)h_s;
    const int feat_first = b * 256 + (d ? 192 : 0) + lane;
    const int feat_last  = b * 256 + (d ? 64 : 128) + lane;

    for (int sb = 0; sb < T_LEN; sb += PF) {
        #pragma unroll
        for (int j = 0; j < PF; ++j) {
            const int s = sb + j;
            float xcur = pr[j];
            if (s + PF < T_LEN) pr[j] = (float)*pf;   // uniform refill
            pf += sstep;

            // gate dot: bh + W[row,:] . h   (4 partial chains)
            float a0 = bh, a1 = 0.f, a2 = 0.f, a3 = 0.f;
            #pragma unroll
            for (int k = 0; k < 16; k += 4) {
                float4 h0 = h4[k], h1 = h4[k + 1], h2 = h4[k + 2], h3 = h4[k + 3];
                a0 = fmaf(w4[k].x,   h0.x, a0); a0 = fmaf(w4[k].y,   h0.y, a0);
                a0 = fmaf(w4[k].z,   h0.z, a0); a0 = fmaf(w4[k].w,   h0.w, a0);
                a1 = fmaf(w4[k+1].x, h1.x, a1); a1 = fmaf(w4[k+1].y, h1.y, a1);
                a1 = fmaf(w4[k+1].z, h1.z, a1); a1 = fmaf(w4[k+1].w, h1.w, a1);
                a2 = fmaf(w4[k+2].x, h2.x, a2); a2 = fmaf(w4[k+2].y, h2.y, a2);
                a2 = fmaf(w4[k+2].z, h2.z, a2); a2 = fmaf(w4[k+2].w, h2.w, a2);
                a3 = fmaf(w4[k+3].x, h3.x, a3); a3 = fmaf(w4[k+3].y, h3.y, a3);
                a3 = fmaf(w4[k+3].z, h3.z, a3); a3 = fmaf(w4[k+3].w, h3.w, a3);
            }
            const float gv = (a0 + a1) + (a2 + a3);

            if (wg == 0) r_s[lane] = sigm_f(xcur + gv);
            else if (wg == 1) z_s[lane] = sigm_f(xcur + gv);
            __syncthreads();   // r_s/z_s visible; all dots done reading h_s

            if (wg == 2) {
                float n = tanh_f(xcur + r_s[lane] * gv);
                float z = z_s[lane];
                hreg = (1.f - z) * n + z * hreg;
                h_s[lane] = hreg;
                if (s == 0)         feat[feat_first] = hreg;
                if (s == T_LEN - 1) feat[feat_last]  = hreg;
            }
            __syncthreads();   // h_s visible for next step
        }
    }
}

// ---------------------------------------------------------------------------
// Kernel 3: MLP head. feat[b][256] -> 32 (LeakyReLU) -> 1
// ---------------------------------------------------------------------------
__global__ __launch_bounds__(64) void head_k(
    const float* __restrict__ feat,
    const float* __restrict__ W1, const float* __restrict__ b1,
    const float* __restrict__ W2, const float* __restrict__ b2,
    float* __restrict__ out)
{
    __shared__ float fs[256];
    const int b = blockIdx.x;
    const int tid = threadIdx.x;
    *(float4*)&fs[tid * 4] = *(const float4*)&feat[b * 256 + tid * 4];
    __syncthreads();
    float v = 0.f;
    if (tid < 32) {
        float a = b1[tid];
        const float4* Wv = (const float4*)(W1 + tid * 256);
        const float4* fv = (const float4*)fs;
        #pragma unroll 8
        for (int k = 0; k < 64; ++k) {
            float4 wv = Wv[k], f = fv[k];
            a += wv.x * f.x + wv.y * f.y + wv.z * f.z + wv.w * f.w;
        }
        a = a >= 0.f ? a : 0.01f * a;
        v = a * W2[tid];
    }
    #pragma unroll
    for (int off = 16; off > 0; off >>= 1) v += __shfl_down(v, off);
    if (tid == 0) out[b] = v + b2[0];
}

// ---------------------------------------------------------------------------
extern "C" void kernel_launch(void* const* d_in, const int* in_sizes, int n_in,
                              void* d_out, int out_size, void* d_ws, size_t ws_size,
                              hipStream_t stream)
{
    const float* x    = (const float*)d_in[0];
    const float* Wihf = (const float*)d_in[1];
    const float* Whhf = (const float*)d_in[2];
    const float* bihf = (const float*)d_in[3];
    const float* bhhf = (const float*)d_in[4];
    const float* Wihb = (const float*)d_in[5];
    const float* Whhb = (const float*)d_in[6];
    const float* bihb = (const float*)d_in[7];
    const float* bhhb = (const float*)d_in[8];
    const float* W1   = (const float*)d_in[9];
    const float* b1   = (const float*)d_in[10];
    const float* W2   = (const float*)d_in[11];
    const float* b2   = (const float*)d_in[12];
    float* out = (float*)d_out;

    _Float16* xp16 = (_Float16*)d_ws;                        // 2*512*256*192 f16 = 100.7 MB
    float*    feat = (float*)((char*)d_ws + (size_t)2 * T_LEN * B_SZ * G3 * 2);

    dim3 gg(2, 1024);
    proj_gemm<<<gg, 256, 0, stream>>>(x, Wihf, bihf, Wihb, bihb, xp16);
    gru_scan<<<512, 192, 0, stream>>>(xp16, Whhf, bhhf, Whhb, bhhb, feat);
    head_k<<<256, 64, 0, stream>>>(feat, W1, b1, W2, b2, out);
}

// Round 5
// 669.390 us; speedup vs baseline: 1.0689x; 1.0410x over previous
//
#include <hip/hip_runtime.h>
#include <hip/hip_bf16.h>
#include <math.h>

#define T_LEN 512
#define B_SZ  256
#define I_SZ  300
#define H_SZ  64
#define G3    192   // 3H

typedef float    f4v __attribute__((ext_vector_type(4)));
typedef _Float16 h2v __attribute__((ext_vector_type(2)));
typedef _Float16 h4v __attribute__((ext_vector_type(4)));
typedef _Float16 h8v __attribute__((ext_vector_type(8)));

__device__ __forceinline__ float dot2(int w, h2v h, float c) {
#if __has_builtin(__builtin_amdgcn_fdot2)
    return __builtin_amdgcn_fdot2(__builtin_bit_cast(h2v, w), h, c, false);
#else
    h2v wv = __builtin_bit_cast(h2v, w);
    return c + (float)wv.x * (float)h.x + (float)wv.y * (float)h.y;
#endif
}

// ---------------------------------------------------------------------------
// Kernel 1: input projection, f16 MFMA, 8-wave blocks, frag-packed LDS.
//   C[m=(t,b)][n=(d,g)] = X[m][k] . W[n][k] + bias[n]
//   Wave tile 64x48 (acc[4][3] = 48 VGPRs) -> ~110 VGPRs -> 4 waves/SIMD.
//   LDS is written in MFMA-fragment order: frag read = &buf[tile*512 + lane*8]
//   (64 lanes x 16 B consecutive -> conflict-free ds_read_b128).
// ---------------------------------------------------------------------------
#define NKC 10

__global__ __launch_bounds__(512, 4) void proj_gemm(
    const float* __restrict__ x,
    const float* __restrict__ Wf, const float* __restrict__ bf,
    const float* __restrict__ Wb, const float* __restrict__ bb,
    _Float16* __restrict__ xp)
{
    __shared__ _Float16 Ap[8 * 512];    // 8 m-tiles, 1 KB each
    __shared__ _Float16 Bp[12 * 512];   // 12 n-tiles

    const int tid = threadIdx.x;         // 0..511
    const int d   = blockIdx.x;
    const int m0  = blockIdx.y * 128;
    const int t_blk = m0 >> 8;
    const int b0    = m0 & 255;

    const float* W    = d ? Wb : Wf;
    const float* bias = d ? bb : bf;

    // staging: q = tid + j*512; lrow = q>>3; lq = q&7 (float4 index, k = lq*4)
    const int srow = tid >> 3;           // 0..63
    const int slq  = tid & 7;

    // MFMA lane mapping
    const int lane = tid & 63;
    const int w    = tid >> 6;           // 0..7
    const int wm   = (w & 1) * 64;
    const int wn   = (w >> 1) * 48;

    // global pointers (A: 2 rows/thread, B: 3 rows/thread)
    const float* aptr[2];
    int aoff[2];
    #pragma unroll
    for (int j = 0; j < 2; ++j) {
        int lrow = (tid + j * 512) >> 3;          // 0..127
        aptr[j] = x + (size_t)((b0 + lrow) * T_LEN + t_blk) * I_SZ + slq * 4;
        aoff[j] = (lrow >> 4) * 512 + (slq >> 1) * 128 + (lrow & 15) * 8 + (slq & 1) * 4;
    }
    const float* bptr[3];
    int boff[3];
    #pragma unroll
    for (int j = 0; j < 3; ++j) {
        int lrow = (tid + j * 512) >> 3;          // 0..191
        bptr[j] = W + (size_t)lrow * I_SZ + slq * 4;
        boff[j] = (lrow >> 4) * 512 + (slq >> 1) * 128 + (lrow & 15) * 8 + (slq & 1) * 4;
    }

    f4v acc[4][3];
    #pragma unroll
    for (int mt = 0; mt < 4; ++mt)
        #pragma unroll
        for (int nt = 0; nt < 3; ++nt) acc[mt][nt] = (f4v)0.f;

    // prefetch chunk 0
    float4 av[2], bv[3];
    {
        const bool valid = (slq * 4) <= 296;
        #pragma unroll
        for (int j = 0; j < 2; ++j)
            av[j] = valid ? *(const float4*)aptr[j] : float4{0.f, 0.f, 0.f, 0.f};
        #pragma unroll
        for (int j = 0; j < 3; ++j)
            bv[j] = valid ? *(const float4*)bptr[j] : float4{0.f, 0.f, 0.f, 0.f};
    }

    for (int kc = 0; kc < NKC; ++kc) {
        __syncthreads();   // previous chunk's fragment reads done

        // ---- convert + frag-packed LDS write ----
        #pragma unroll
        for (int j = 0; j < 2; ++j) {
            h4v c = { (_Float16)av[j].x, (_Float16)av[j].y,
                      (_Float16)av[j].z, (_Float16)av[j].w };
            *(h4v*)&Ap[aoff[j]] = c;
        }
        #pragma unroll
        for (int j = 0; j < 3; ++j) {
            h4v c = { (_Float16)bv[j].x, (_Float16)bv[j].y,
                      (_Float16)bv[j].z, (_Float16)bv[j].w };
            *(h4v*)&Bp[boff[j]] = c;
        }
        __syncthreads();

        // ---- issue next chunk's loads (fly during MFMAs) ----
        if (kc + 1 < NKC) {
            const int k0 = (kc + 1) * 32;
            const bool valid = (k0 + slq * 4) <= 296;
            #pragma unroll
            for (int j = 0; j < 2; ++j)
                av[j] = valid ? *(const float4*)(aptr[j] + k0) : float4{0.f, 0.f, 0.f, 0.f};
            #pragma unroll
            for (int j = 0; j < 3; ++j)
                bv[j] = valid ? *(const float4*)(bptr[j] + k0) : float4{0.f, 0.f, 0.f, 0.f};
        }

        // ---- fragment loads (conflict-free) + MFMA ----
        h8v bh_[3];
        #pragma unroll
        for (int nt = 0; nt < 3; ++nt)
            bh_[nt] = *(const h8v*)&Bp[((wn >> 4) + nt) * 512 + lane * 8];
        #pragma unroll
        for (int mt = 0; mt < 4; ++mt) {
            h8v ah = *(const h8v*)&Ap[((wm >> 4) + mt) * 512 + lane * 8];
            #pragma unroll
            for (int nt = 0; nt < 3; ++nt)
                acc[mt][nt] = __builtin_amdgcn_mfma_f32_16x16x32_f16(ah, bh_[nt], acc[mt][nt], 0, 0, 0);
        }
    }

    // ---- epilogue: bias + paired-lane dword f16 stores ----
    const int col  = lane & 15;
    const int rowq = lane >> 4;
    float bias_v[3];
    #pragma unroll
    for (int nt = 0; nt < 3; ++nt) bias_v[nt] = bias[wn + nt * 16 + col];

    #pragma unroll
    for (int mt = 0; mt < 4; ++mt) {
        #pragma unroll
        for (int reg = 0; reg < 4; ++reg) {
            int b = b0 + wm + mt * 16 + rowq * 4 + reg;
            _Float16* o = xp + ((size_t)(d * T_LEN + t_blk) * B_SZ + b) * G3;
            #pragma unroll
            for (int nt = 0; nt < 3; ++nt) {
                float v = acc[mt][nt][reg] + bias_v[nt];
                float pv = __shfl_xor(v, 1);          // partner col c^1, same row
                if ((lane & 1) == 0) {
                    unsigned lo = (unsigned)__builtin_bit_cast(unsigned short, (_Float16)v);
                    unsigned hi = (unsigned)__builtin_bit_cast(unsigned short, (_Float16)pv);
                    int g = wn + nt * 16 + col;       // even
                    *(unsigned*)(o + g) = (hi << 16) | lo;
                }
            }
        }
    }
}

// ---------------------------------------------------------------------------
// Kernel 2: GRU scan — one wave per (dir,batch), barrier-free; W pinned in
// VGPRs via empty-asm launder (R1-R4 showed the compiler otherwise
// rematerializes the loop-invariant W loads from global every step:
// VGPR_Count 52 vs the 64+ needed — that was the 390 µs).
// ---------------------------------------------------------------------------
#define PF 4

__device__ __forceinline__ float sigm_f(float x) {
    return __builtin_amdgcn_rcpf(1.f + __expf(-x));
}
__device__ __forceinline__ float tanh_f(float x) {
    float a = fabsf(x);
    float e = __expf(2.f * a);
    float t = 1.f - 2.f * __builtin_amdgcn_rcpf(1.f + e);
    return copysignf(t, x);
}

__global__ __launch_bounds__(64) void gru_scan(
    const _Float16* __restrict__ xp,
    const float* __restrict__ Whf, const float* __restrict__ bhf,
    const float* __restrict__ Whb, const float* __restrict__ bhb,
    float* __restrict__ feat)
{
    const int lane = threadIdx.x;
    const int bid  = blockIdx.x;       // 0..511
    const int d    = bid >> 8;
    const int b    = bid & 255;

    const float* Whh = d ? Whb : Whf;
    const float* bhh = d ? bhb : bhf;

    // W_hh rows for this lane's 3 gates, packed f16 pairs held as ints
    int wri[32], wzi[32], wni[32];
    {
        const float2* r0 = (const float2*)(Whh + (size_t)lane * 64);
        const float2* r1 = (const float2*)(Whh + (size_t)(64 + lane) * 64);
        const float2* r2 = (const float2*)(Whh + (size_t)(128 + lane) * 64);
        #pragma unroll
        for (int k = 0; k < 32; ++k) {
            float2 a = r0[k], c = r1[k], e = r2[k];
            wri[k] = __builtin_bit_cast(int, h2v{(_Float16)a.x, (_Float16)a.y});
            wzi[k] = __builtin_bit_cast(int, h2v{(_Float16)c.x, (_Float16)c.y});
            wni[k] = __builtin_bit_cast(int, h2v{(_Float16)e.x, (_Float16)e.y});
        }
    }
    // Launder: make values opaque so the compiler cannot re-materialize the
    // loads inside the step loop — forces true VGPR residency.
    #pragma unroll
    for (int k = 0; k < 32; ++k)
        asm volatile("" : "+v"(wri[k]), "+v"(wzi[k]), "+v"(wni[k]));

    const float bhr = bhh[lane], bhz = bhh[64 + lane], bhn = bhh[128 + lane];

    __shared__ _Float16 h16s[64];
    h16s[lane] = (_Float16)0.f;
    float hreg = 0.f;
    __syncthreads();

    const long sstep = d ? -(long)(B_SZ * G3) : (long)(B_SZ * G3);
    const _Float16* xb0 = xp + ((size_t)(d ? (2 * T_LEN - 1) : 0) * B_SZ + b) * G3;

    _Float16 pr[PF], pz[PF], pn[PF];
    #pragma unroll
    for (int j = 0; j < PF; ++j) {
        const _Float16* p = xb0 + j * sstep;
        pr[j] = p[lane]; pz[j] = p[64 + lane]; pn[j] = p[128 + lane];
    }
    const _Float16* pf = xb0 + PF * sstep;

    const h2v* hp = (const h2v*)h16s;

    for (int sb = 0; sb < T_LEN; sb += PF) {
        #pragma unroll
        for (int j = 0; j < PF; ++j) {
            const int s = sb + j;
            float xr = (float)pr[j], xz = (float)pz[j], xn = (float)pn[j];
            if (s + PF < T_LEN) {            // uniform branch; refill slot j
                pr[j] = pf[lane]; pz[j] = pf[64 + lane]; pn[j] = pf[128 + lane];
            }
            pf += sstep;

            float ar0 = 0.f, ar1 = 0.f, az0 = 0.f, az1 = 0.f, an0 = 0.f, an1 = 0.f;
            #pragma unroll
            for (int k = 0; k < 32; k += 2) {
                h2v h0 = hp[k], h1 = hp[k + 1];   // uniform ds_read_b32
                ar0 = dot2(wri[k],     h0, ar0);
                az0 = dot2(wzi[k],     h0, az0);
                an0 = dot2(wni[k],     h0, an0);
                ar1 = dot2(wri[k + 1], h1, ar1);
                az1 = dot2(wzi[k + 1], h1, az1);
                an1 = dot2(wni[k + 1], h1, an1);
            }
            float r  = sigm_f(xr + bhr + ar0 + ar1);
            float z  = sigm_f(xz + bhz + az0 + az1);
            float hn = bhn + an0 + an1;
            float n  = tanh_f(xn + r * hn);
            hreg = (1.f - z) * n + z * hreg;
            h16s[lane] = (_Float16)hreg;       // single-wave: no barrier needed
            if (s == 0)         feat[b * 256 + (d ? 192 : 0) + lane] = hreg;
            if (s == T_LEN - 1) feat[b * 256 + (d ? 64 : 128) + lane] = hreg;
        }
    }
}

// ---------------------------------------------------------------------------
// Kernel 3: MLP head. feat[b][256] -> 32 (LeakyReLU) -> 1
// ---------------------------------------------------------------------------
__global__ __launch_bounds__(64) void head_k(
    const float* __restrict__ feat,
    const float* __restrict__ W1, const float* __restrict__ b1,
    const float* __restrict__ W2, const float* __restrict__ b2,
    float* __restrict__ out)
{
    __shared__ float fs[256];
    const int b = blockIdx.x;
    const int tid = threadIdx.x;
    *(float4*)&fs[tid * 4] = *(const float4*)&feat[b * 256 + tid * 4];
    __syncthreads();
    float v = 0.f;
    if (tid < 32) {
        float a = b1[tid];
        const float4* Wv = (const float4*)(W1 + tid * 256);
        const float4* fv = (const float4*)fs;
        #pragma unroll 8
        for (int k = 0; k < 64; ++k) {
            float4 wv = Wv[k], f = fv[k];
            a += wv.x * f.x + wv.y * f.y + wv.z * f.z + wv.w * f.w;
        }
        a = a >= 0.f ? a : 0.01f * a;
        v = a * W2[tid];
    }
    #pragma unroll
    for (int off = 16; off > 0; off >>= 1) v += __shfl_down(v, off);
    if (tid == 0) out[b] = v + b2[0];
}

// ---------------------------------------------------------------------------
extern "C" void kernel_launch(void* const* d_in, const int* in_sizes, int n_in,
                              void* d_out, int out_size, void* d_ws, size_t ws_size,
                              hipStream_t stream)
{
    const float* x    = (const float*)d_in[0];
    const float* Wihf = (const float*)d_in[1];
    const float* Whhf = (const float*)d_in[2];
    const float* bihf = (const float*)d_in[3];
    const float* bhhf = (const float*)d_in[4];
    const float* Wihb = (const float*)d_in[5];
    const float* Whhb = (const float*)d_in[6];
    const float* bihb = (const float*)d_in[7];
    const float* bhhb = (const float*)d_in[8];
    const float* W1   = (const float*)d_in[9];
    const float* b1   = (const float*)d_in[10];
    const float* W2   = (const float*)d_in[11];
    const float* b2   = (const float*)d_in[12];
    float* out = (float*)d_out;

    _Float16* xp16 = (_Float16*)d_ws;                        // 2*512*256*192 f16 = 100.7 MB
    float*    feat = (float*)((char*)d_ws + (size_t)2 * T_LEN * B_SZ * G3 * 2);

    dim3 gg(2, 1024);
    proj_gemm<<<gg, 512, 0, stream>>>(x, Wihf, bihf, Wihb, bihb, xp16);
    gru_scan<<<512, 64, 0, stream>>>(xp16, Whhf, bhhf, Whhb, bhhb, feat);
    head_k<<<256, 64, 0, stream>>>(feat, W1, b1, W2, b2, out);
}